// Round 1
// baseline (456.058 us; speedup 1.0000x reference)
//
#include <hip/hip_runtime.h>
#include <hip/hip_bf16.h>

#define NN 20000
#define MM 32
#define EE 20
#define HH 128

// ---------- helpers ----------
__device__ __forceinline__ float bf_lo(unsigned int u) {
    return __uint_as_float(u << 16);
}
__device__ __forceinline__ float bf_hi(unsigned int u) {
    return __uint_as_float(u & 0xFFFF0000u);
}
__device__ __forceinline__ unsigned int pack_bf2(float lo, float hi) {
    // round-to-nearest-even bf16 pack: lo -> bits[15:0], hi -> bits[31:16]
    unsigned int a = __float_as_uint(lo);
    unsigned int b = __float_as_uint(hi);
    a += 0x7FFFu + ((a >> 16) & 1u);
    b += 0x7FFFu + ((b >> 16) & 1u);
    return (a >> 16) | (b & 0xFFFF0000u);
}
__device__ __forceinline__ float softplusf(float x) {
    return fmaxf(x, 0.f) + __logf(1.f + __expf(-fabsf(x)));
}

// ---------- kernel 1: build Wcat (128 x 1024, pair-encoded cols) ----------
// col c: b=c>>9 (che/vdw), sec=(c>>8)&1 (self/nbr), h=(c>>1)&127, slot=c&1 (filt/core)
// Wcat[k][c] = Wfull_b[(sec?256:0)+k][slot*128+h]
__global__ void build_wcat(const float* __restrict__ cheW,
                           const float* __restrict__ vdwW,
                           float* __restrict__ Wcat) {
    int t = blockIdx.x * 256 + threadIdx.x;   // < 131072
    int k = t >> 10;
    int c = t & 1023;
    int b = c >> 9, sec = (c >> 8) & 1, h = (c >> 1) & 127, slot = c & 1;
    const float* W = b ? vdwW : cheW;
    int row = (sec ? 256 : 0) + k;
    Wcat[t] = W[row * 256 + slot * 128 + h];
}

// ---------- kernel 2: build WfW (2 x 20 x 512) and fused bias (2 x 512) ----------
// pair col c in [0,512): h=c>>1, slot=c&1 -> jcol = slot*128 + h
// WfW[b][e][c] = sum_h2 Wf_b[e][h2] * Wfull_b[128+h2][jcol]
// bias[b][c]   = bfull_b[jcol] + sum_h2 bf_b[h2] * Wfull_b[128+h2][jcol]
__global__ void build_wfw(const float* __restrict__ cheWf, const float* __restrict__ cheBf,
                          const float* __restrict__ cheW,  const float* __restrict__ cheBfull,
                          const float* __restrict__ vdwWf, const float* __restrict__ vdwBf,
                          const float* __restrict__ vdwW,  const float* __restrict__ vdwBfull,
                          float* __restrict__ WfW, float* __restrict__ biasP) {
    int t = blockIdx.x * 256 + threadIdx.x;   // < 1024
    int b = t >> 9, c = t & 511;
    int jcol = (c & 1) * 128 + (c >> 1);
    const float* Wf    = b ? vdwWf    : cheWf;
    const float* bfv   = b ? vdwBf    : cheBf;
    const float* W     = b ? vdwW     : cheW;
    const float* bfull = b ? vdwBfull : cheBfull;

    float s = bfull[jcol];
    for (int h2 = 0; h2 < 128; ++h2)
        s = fmaf(bfv[h2], W[(128 + h2) * 256 + jcol], s);
    biasP[b * 512 + c] = s;

    for (int e = 0; e < EE; ++e) {
        float a = 0.f;
        for (int h2 = 0; h2 < 128; ++h2)
            a = fmaf(Wf[e * 128 + h2], W[(128 + h2) * 256 + jcol], a);
        WfW[(b * EE + e) * 512 + c] = a;
    }
}

// ---------- kernel 3: proj GEMM  P[n][512] (bf16x2 packed) = nodes @ Wcat ----------
// 16 nodes per block, 256 threads, thread t handles cols 4t..4t+3
__global__ __launch_bounds__(256) void proj_kernel(const float* __restrict__ nodes,
                                                   const float* __restrict__ Wcat,
                                                   unsigned int* __restrict__ P) {
    __shared__ float ln[16 * 128];
    int n0 = blockIdx.x * 16;
    int t = threadIdx.x;
    for (int i = t; i < 2048; i += 256) ln[i] = nodes[n0 * 128 + i];
    __syncthreads();

    float4 acc[16];
#pragma unroll
    for (int i = 0; i < 16; ++i) acc[i] = make_float4(0.f, 0.f, 0.f, 0.f);

    int c0 = t * 4;
    for (int k = 0; k < 128; k += 4) {
        float4 w0 = *(const float4*)&Wcat[(k + 0) * 1024 + c0];
        float4 w1 = *(const float4*)&Wcat[(k + 1) * 1024 + c0];
        float4 w2 = *(const float4*)&Wcat[(k + 2) * 1024 + c0];
        float4 w3 = *(const float4*)&Wcat[(k + 3) * 1024 + c0];
#pragma unroll
        for (int ni = 0; ni < 16; ++ni) {
            float4 nv = *(const float4*)&ln[ni * 128 + k];
            acc[ni].x = fmaf(nv.x, w0.x, acc[ni].x);
            acc[ni].y = fmaf(nv.x, w0.y, acc[ni].y);
            acc[ni].z = fmaf(nv.x, w0.z, acc[ni].z);
            acc[ni].w = fmaf(nv.x, w0.w, acc[ni].w);
            acc[ni].x = fmaf(nv.y, w1.x, acc[ni].x);
            acc[ni].y = fmaf(nv.y, w1.y, acc[ni].y);
            acc[ni].z = fmaf(nv.y, w1.z, acc[ni].z);
            acc[ni].w = fmaf(nv.y, w1.w, acc[ni].w);
            acc[ni].x = fmaf(nv.z, w2.x, acc[ni].x);
            acc[ni].y = fmaf(nv.z, w2.y, acc[ni].y);
            acc[ni].z = fmaf(nv.z, w2.z, acc[ni].z);
            acc[ni].w = fmaf(nv.z, w2.w, acc[ni].w);
            acc[ni].x = fmaf(nv.w, w3.x, acc[ni].x);
            acc[ni].y = fmaf(nv.w, w3.y, acc[ni].y);
            acc[ni].z = fmaf(nv.w, w3.z, acc[ni].z);
            acc[ni].w = fmaf(nv.w, w3.w, acc[ni].w);
        }
    }
#pragma unroll
    for (int ni = 0; ni < 16; ++ni) {
        uint2 uu;
        uu.x = pack_bf2(acc[ni].x, acc[ni].y);  // (filt,core) for h=2t
        uu.y = pack_bf2(acc[ni].z, acc[ni].w);  // (filt,core) for h=2t+1
        *(uint2*)&P[(n0 + ni) * 512 + t * 2] = uu;
    }
}

// ---------- kernel 4: main fused gather + gate + reduce ----------
// one block per node, 128 threads (thread = output channel h)
__global__ __launch_bounds__(128) void main_kernel(
    const float* __restrict__ nodes,
    const float* __restrict__ rbf_che, const int* __restrict__ idx_che,
    const float* __restrict__ rbf_vdw, const int* __restrict__ idx_vdw,
    const unsigned int* __restrict__ P,
    const float* __restrict__ WfW, const float* __restrict__ biasP,
    float* __restrict__ out) {
    __shared__ float srbf[2][MM * 24];  // padded stride 24 for b128 reads
    __shared__ int sidx[2][MM];
    int n = blockIdx.x;
    int h = threadIdx.x;

    for (int i = h; i < MM * EE; i += 128) {
        int m = i / EE, e = i - m * EE;
        srbf[0][m * 24 + e] = rbf_che[n * (MM * EE) + i];
        srbf[1][m * 24 + e] = rbf_vdw[n * (MM * EE) + i];
    }
    if (h < MM) {
        sidx[0][h] = idx_che[n * MM + h];
        sidx[1][h] = idx_vdw[n * MM + h];
    }
    __syncthreads();

    float acc = 0.f;
#pragma unroll
    for (int b = 0; b < 2; ++b) {
        float2 wf[EE];
        const float* wbase = WfW + b * EE * 512 + 2 * h;
#pragma unroll
        for (int e = 0; e < EE; ++e) wf[e] = *(const float2*)&wbase[e * 512];
        float2 bias = *(const float2*)&biasP[b * 512 + 2 * h];

        unsigned int su = P[n * 512 + b * 256 + h];  // self section
        float baseF = bf_lo(su) + bias.x;
        float baseC = bf_hi(su) + bias.y;

        for (int m = 0; m < MM; ++m) {
            int idx = sidx[b][m];
            unsigned int g = P[idx * 512 + b * 256 + 128 + h];  // nbr section
            float dotf = 0.f, dotc = 0.f;
#pragma unroll
            for (int e = 0; e < EE; ++e) {
                float r = srbf[b][m * 24 + e];
                dotf = fmaf(r, wf[e].x, dotf);
                dotc = fmaf(r, wf[e].y, dotc);
            }
            float filt = baseF + bf_lo(g) + dotf;
            float core = baseC + bf_hi(g) + dotc;
            float sg = __builtin_amdgcn_rcpf(1.f + __expf(-filt));
            float sp = softplusf(core);
            acc = fmaf(sg, sp, acc);
        }
    }
    float x = nodes[n * 128 + h] + acc;
    out[n * 128 + h] = softplusf(x);
}

// ---------- launch ----------
extern "C" void kernel_launch(void* const* d_in, const int* in_sizes, int n_in,
                              void* d_out, int out_size, void* d_ws, size_t ws_size,
                              hipStream_t stream) {
    const float* nodes     = (const float*)d_in[0];
    const float* che_rbf   = (const float*)d_in[1];
    const int*   che_idx   = (const int*)d_in[2];
    const float* vdw_rbf   = (const float*)d_in[3];
    const int*   vdw_idx   = (const int*)d_in[4];
    const float* che_Wf    = (const float*)d_in[5];
    const float* che_bf    = (const float*)d_in[6];
    const float* che_Wfull = (const float*)d_in[7];
    const float* che_bfull = (const float*)d_in[8];
    const float* vdw_Wf    = (const float*)d_in[9];
    const float* vdw_bf    = (const float*)d_in[10];
    const float* vdw_Wfull = (const float*)d_in[11];
    const float* vdw_bfull = (const float*)d_in[12];

    char* ws = (char*)d_ws;
    float* Wcat         = (float*)ws;                               // 512 KB
    float* WfW          = (float*)(ws + 524288);                    // 80 KB
    float* biasP        = (float*)(ws + 524288 + 81920);            // 4 KB
    unsigned int* P     = (unsigned int*)(ws + 524288 + 81920 + 4096); // 40.96 MB

    build_wcat<<<512, 256, 0, stream>>>(che_Wfull, vdw_Wfull, Wcat);
    build_wfw<<<4, 256, 0, stream>>>(che_Wf, che_bf, che_Wfull, che_bfull,
                                     vdw_Wf, vdw_bf, vdw_Wfull, vdw_bfull,
                                     WfW, biasP);
    proj_kernel<<<NN / 16, 256, 0, stream>>>(nodes, Wcat, P);
    main_kernel<<<NN, 128, 0, stream>>>(nodes, che_rbf, che_idx, vdw_rbf, vdw_idx,
                                        P, WfW, biasP, (float*)d_out);
}

// Round 3
// 305.340 us; speedup vs baseline: 1.4936x; 1.4936x over previous
//
#include <hip/hip_runtime.h>
#include <hip/hip_bf16.h>

#define NN 20000
#define MM 32
#define EE 20
#define HH 128

typedef __attribute__((ext_vector_type(8))) short bf16x8;
typedef __attribute__((ext_vector_type(4))) float f32x4;

// ---------- helpers ----------
__device__ __forceinline__ float bf_lo(unsigned int u) {
    return __uint_as_float(u << 16);
}
__device__ __forceinline__ float bf_hi(unsigned int u) {
    return __uint_as_float(u & 0xFFFF0000u);
}
__device__ __forceinline__ unsigned int pack_bf2(float lo, float hi) {
    unsigned int a = __float_as_uint(lo);
    unsigned int b = __float_as_uint(hi);
    a += 0x7FFFu + ((a >> 16) & 1u);
    b += 0x7FFFu + ((b >> 16) & 1u);
    return (a >> 16) | (b & 0xFFFF0000u);
}
__device__ __forceinline__ unsigned short bf16r(float v) {
    unsigned int u = __float_as_uint(v);
    u += 0x7FFFu + ((u >> 16) & 1u);
    return (unsigned short)(u >> 16);
}
__device__ __forceinline__ float softplusf(float x) {
    return fmaxf(x, 0.f) + __logf(1.f + __expf(-fabsf(x)));
}

// ---------- kernel 1: build Wcat (128 x 1024, pair-encoded cols) ----------
// col c: b=c>>9 (che/vdw), sec=(c>>8)&1 (self/nbr), h=(c>>1)&127, slot=c&1 (filt/core)
__global__ void build_wcat(const float* __restrict__ cheW,
                           const float* __restrict__ vdwW,
                           float* __restrict__ Wcat) {
    int t = blockIdx.x * 256 + threadIdx.x;   // < 131072
    int k = t >> 10;
    int c = t & 1023;
    int b = c >> 9, sec = (c >> 8) & 1, h = (c >> 1) & 127, slot = c & 1;
    const float* W = b ? vdwW : cheW;
    int row = (sec ? 256 : 0) + k;
    Wcat[t] = W[row * 256 + slot * 128 + h];
}

// ---------- kernel 2: build Bfrag (MFMA B fragments of WfW, bf16) + biasP ----------
// Bfrag element index: (((b*2+w)*8+tc)*64 + l)*8 + i       (2048 fragments)
//   wave w in {0,1} covers h in [w*64, w*64+64); c-tile tc: h = w*64 + (tc>>1)*16 + (l&15),
//   slot = tc&1, jcol = slot*128 + h; k = (l>>4)*8 + i (pad k>=20 with 0).
// biasP[t] for t<512: [b][slot][h] = bfull[jcol] + sum_h2 bf[h2]*Wfull[128+h2][jcol]
__global__ void build_bfrag(const float* __restrict__ cheWf, const float* __restrict__ cheBf,
                            const float* __restrict__ cheW,  const float* __restrict__ cheBfull,
                            const float* __restrict__ vdwWf, const float* __restrict__ vdwBf,
                            const float* __restrict__ vdwW,  const float* __restrict__ vdwBfull,
                            unsigned short* __restrict__ Bfrag, float* __restrict__ biasP) {
    int t = blockIdx.x * 256 + threadIdx.x;   // < 2048
    int b = t >> 10, w = (t >> 9) & 1, tc = (t >> 6) & 7, l = t & 63;
    int lhi = l >> 4, llo = l & 15;
    int h = w * 64 + (tc >> 1) * 16 + llo;    // < 128
    int slot = tc & 1;
    int jcol = slot * 128 + h;                // < 256
    const float* Wf = b ? vdwWf : cheWf;
    const float* W  = b ? vdwW  : cheW;

    unsigned short o[8];
#pragma unroll
    for (int i = 0; i < 8; ++i) {
        int k = lhi * 8 + i;
        float a = 0.f;
        if (k < EE)
            for (int h2 = 0; h2 < 128; ++h2)
                a = fmaf(Wf[k * 128 + h2], W[(128 + h2) * 256 + jcol], a);
        o[i] = bf16r(a);
    }
#pragma unroll
    for (int i = 0; i < 8; ++i) Bfrag[t * 8 + i] = o[i];

    if (t < 512) {
        int bb = t >> 8, sl = (t >> 7) & 1, hh = t & 127;
        int jc = sl * 128 + hh;
        const float* bfv   = bb ? vdwBf    : cheBf;
        const float* Wb    = bb ? vdwW     : cheW;
        const float* bfull = bb ? vdwBfull : cheBfull;
        float s = bfull[jc];
        for (int h2 = 0; h2 < 128; ++h2)
            s = fmaf(bfv[h2], Wb[(128 + h2) * 256 + jc], s);
        biasP[t] = s;
    }
}

// ---------- kernel 3: proj GEMM  P[n][512] (bf16x2 packed) = nodes @ Wcat ----------
__global__ __launch_bounds__(256) void proj_kernel(const float* __restrict__ nodes,
                                                   const float* __restrict__ Wcat,
                                                   unsigned int* __restrict__ P) {
    __shared__ float ln[16 * 128];
    int n0 = blockIdx.x * 16;
    int t = threadIdx.x;
    for (int i = t; i < 2048; i += 256) ln[i] = nodes[n0 * 128 + i];
    __syncthreads();

    float4 acc[16];
#pragma unroll
    for (int i = 0; i < 16; ++i) acc[i] = make_float4(0.f, 0.f, 0.f, 0.f);

    int c0 = t * 4;
    for (int k = 0; k < 128; k += 4) {
        float4 w0 = *(const float4*)&Wcat[(k + 0) * 1024 + c0];
        float4 w1 = *(const float4*)&Wcat[(k + 1) * 1024 + c0];
        float4 w2 = *(const float4*)&Wcat[(k + 2) * 1024 + c0];
        float4 w3 = *(const float4*)&Wcat[(k + 3) * 1024 + c0];
#pragma unroll
        for (int ni = 0; ni < 16; ++ni) {
            float4 nv = *(const float4*)&ln[ni * 128 + k];
            acc[ni].x = fmaf(nv.x, w0.x, acc[ni].x);
            acc[ni].y = fmaf(nv.x, w0.y, acc[ni].y);
            acc[ni].z = fmaf(nv.x, w0.z, acc[ni].z);
            acc[ni].w = fmaf(nv.x, w0.w, acc[ni].w);
            acc[ni].x = fmaf(nv.y, w1.x, acc[ni].x);
            acc[ni].y = fmaf(nv.y, w1.y, acc[ni].y);
            acc[ni].z = fmaf(nv.y, w1.z, acc[ni].z);
            acc[ni].w = fmaf(nv.y, w1.w, acc[ni].w);
            acc[ni].x = fmaf(nv.z, w2.x, acc[ni].x);
            acc[ni].y = fmaf(nv.z, w2.y, acc[ni].y);
            acc[ni].z = fmaf(nv.z, w2.z, acc[ni].z);
            acc[ni].w = fmaf(nv.z, w2.w, acc[ni].w);
            acc[ni].x = fmaf(nv.w, w3.x, acc[ni].x);
            acc[ni].y = fmaf(nv.w, w3.y, acc[ni].y);
            acc[ni].z = fmaf(nv.w, w3.z, acc[ni].z);
            acc[ni].w = fmaf(nv.w, w3.w, acc[ni].w);
        }
    }
#pragma unroll
    for (int ni = 0; ni < 16; ++ni) {
        uint2 uu;
        uu.x = pack_bf2(acc[ni].x, acc[ni].y);
        uu.y = pack_bf2(acc[ni].z, acc[ni].w);
        *(uint2*)&P[(n0 + ni) * 512 + t * 2] = uu;
    }
}

// ---------- kernel 4: main — MFMA edge GEMM + gather + gate + reduce ----------
// one block per node, 128 threads = 2 waves; wave w owns h in [w*64, w*64+64)
__global__ __launch_bounds__(128) void main_kernel(
    const float* __restrict__ nodes,
    const float* __restrict__ rbf_che, const int* __restrict__ idx_che,
    const float* __restrict__ rbf_vdw, const int* __restrict__ idx_vdw,
    const unsigned int* __restrict__ P,
    const unsigned short* __restrict__ Bfrag, const float* __restrict__ biasP,
    float* __restrict__ out) {
    // A staging: [b][m][k] bf16, row padded to 40 elems (80 B, 16B-aligned)
    __shared__ unsigned short sA[2 * 32 * 40];
    __shared__ int sidx[2][MM];
    int n = blockIdx.x;
    int tid = threadIdx.x;
    int w = tid >> 6, l = tid & 63;       // w in {0,1}
    int lhi = l >> 4, llo = l & 15;

    for (int i = tid; i < 2048; i += 128) {
        int b = i >> 10, m = (i >> 5) & 31, k = i & 31;
        float v = 0.f;
        if (k < EE) v = (b ? rbf_vdw : rbf_che)[n * (MM * EE) + m * EE + k];
        sA[(b * 32 + m) * 40 + k] = bf16r(v);
    }
    if (tid < 64) {
        int b = tid >> 5, m = tid & 31;
        sidx[b][m] = (b ? idx_vdw : idx_che)[n * MM + m];
    }
    __syncthreads();

    float psum[4] = {0.f, 0.f, 0.f, 0.f};

#pragma unroll
    for (int b = 0; b < 2; ++b) {
        // B fragments (L2-resident, fragment-order prebuilt)
        bf16x8 Bf[8];
        const unsigned short* bb = Bfrag + (size_t)((b * 2 + w) * 8) * 64 * 8;
#pragma unroll
        for (int tc = 0; tc < 8; ++tc)
            Bf[tc] = *(const bf16x8*)(bb + (tc * 64 + l) * 8);

        // A fragments from LDS (row = tm*16 + llo, k = lhi*8 + i)
        bf16x8 Af[2];
#pragma unroll
        for (int tm = 0; tm < 2; ++tm)
            Af[tm] = *(const bf16x8*)&sA[(b * 32 + tm * 16 + llo) * 40 + lhi * 8];

        // this lane's 8 m-rows' neighbor indices (C/D row = lhi*4 + r)
        int vidx[2][4];
#pragma unroll
        for (int tm = 0; tm < 2; ++tm)
#pragma unroll
            for (int r = 0; r < 4; ++r)
                vidx[tm][r] = sidx[b][tm * 16 + lhi * 4 + r];

        f32x4 acc[2][8];
#pragma unroll
        for (int tm = 0; tm < 2; ++tm)
#pragma unroll
            for (int tc = 0; tc < 8; ++tc)
                acc[tm][tc] = (f32x4){0.f, 0.f, 0.f, 0.f};

#pragma unroll
        for (int tm = 0; tm < 2; ++tm)
#pragma unroll
            for (int tc = 0; tc < 8; ++tc)
                acc[tm][tc] = __builtin_amdgcn_mfma_f32_16x16x32_bf16(
                    Af[tm], Bf[tc], acc[tm][tc], 0, 0, 0);

        // epilogue: add self+bias+nbr, gate, accumulate over this lane's m rows
#pragma unroll
        for (int tp = 0; tp < 4; ++tp) {
            int h = w * 64 + tp * 16 + llo;   // < 128
            unsigned int su = P[n * 512 + b * 256 + h];
            float baseF = biasP[b * 256 + h]       + bf_lo(su);
            float baseC = biasP[b * 256 + 128 + h] + bf_hi(su);
#pragma unroll
            for (int tm = 0; tm < 2; ++tm) {
#pragma unroll
                for (int r = 0; r < 4; ++r) {
                    unsigned int g = P[(size_t)vidx[tm][r] * 512 + b * 256 + 128 + h];
                    float filt = acc[tm][2 * tp][r]     + baseF + bf_lo(g);
                    float core = acc[tm][2 * tp + 1][r] + baseC + bf_hi(g);
                    float sg = __builtin_amdgcn_rcpf(1.f + __expf(-filt));
                    float sp = softplusf(core);
                    psum[tp] = fmaf(sg, sp, psum[tp]);
                }
            }
        }
    }

    // cross-lane reduce over the 4 lhi groups
    float res = 0.f;
#pragma unroll
    for (int tp = 0; tp < 4; ++tp) {
        float v = psum[tp];
        v += __shfl_xor(v, 16);
        v += __shfl_xor(v, 32);
        if (lhi == tp) res = v;
    }
    int h = w * 64 + l;   // < 128
    float x = nodes[n * 128 + h] + res;
    out[n * 128 + h] = softplusf(x);
}

// ---------- launch ----------
extern "C" void kernel_launch(void* const* d_in, const int* in_sizes, int n_in,
                              void* d_out, int out_size, void* d_ws, size_t ws_size,
                              hipStream_t stream) {
    const float* nodes     = (const float*)d_in[0];
    const float* che_rbf   = (const float*)d_in[1];
    const int*   che_idx   = (const int*)d_in[2];
    const float* vdw_rbf   = (const float*)d_in[3];
    const int*   vdw_idx   = (const int*)d_in[4];
    const float* che_Wf    = (const float*)d_in[5];
    const float* che_bf    = (const float*)d_in[6];
    const float* che_Wfull = (const float*)d_in[7];
    const float* che_bfull = (const float*)d_in[8];
    const float* vdw_Wf    = (const float*)d_in[9];
    const float* vdw_bf    = (const float*)d_in[10];
    const float* vdw_Wfull = (const float*)d_in[11];
    const float* vdw_bfull = (const float*)d_in[12];

    char* ws = (char*)d_ws;
    float* Wcat           = (float*)ws;                       // 512 KB
    unsigned short* Bfrag = (unsigned short*)(ws + 524288);   // 32 KB
    float* biasP          = (float*)(ws + 524288 + 32768);    // 2 KB
    unsigned int* P       = (unsigned int*)(ws + 559104);     // 40.96 MB

    build_wcat<<<512, 256, 0, stream>>>(che_Wfull, vdw_Wfull, Wcat);
    build_bfrag<<<8, 256, 0, stream>>>(che_Wf, che_bf, che_Wfull, che_bfull,
                                       vdw_Wf, vdw_bf, vdw_Wfull, vdw_bfull,
                                       Bfrag, biasP);
    proj_kernel<<<NN / 16, 256, 0, stream>>>(nodes, Wcat, P);
    main_kernel<<<NN, 128, 0, stream>>>(nodes, che_rbf, che_idx, vdw_rbf, vdw_idx,
                                        P, Bfrag, biasP, (float*)d_out);
}